// Round 13
// baseline (255.210 us; speedup 1.0000x reference)
//
#include <hip/hip_runtime.h>

// Complex MultiheadAttention, fp16-MFMA implementation for gfx950.
// E=512 H=8 D=64 T=S=2048 B=4. All shapes divide tile sizes exactly.
// Q/K/V stored in MFMA-fragment order (1KB contiguous per wave load).
// pass2: R9 known-good (512 thr, QBLK=32, 4-deep LDS p-pipeline, folded norm).
//        QBLK=64 register-infeasible; QBLK=16 exceeds per-XCD L2 BW; s-split
//        needs workspace beyond known-safe 72MB. Structural plateau ~106 us.
// pass1: 2 t-strips per wave -> K traffic halved (256 blocks).
// inproj: R7 reg-staged + LDS DOUBLE-BUFFER, 1 barrier/K-step (B gloads fly
//         across the MFMA phase instead of draining at an idle barrier).
// outproj: 64x128 tiles, 512 blocks = 2/CU.

typedef _Float16 half8 __attribute__((ext_vector_type(8)));
typedef _Float16 half2v __attribute__((ext_vector_type(2)));
typedef float f32x4 __attribute__((ext_vector_type(4)));
typedef float f32x2 __attribute__((ext_vector_type(2)));
typedef unsigned uint2v __attribute__((ext_vector_type(2)));
typedef unsigned uint4v __attribute__((ext_vector_type(4)));

__device__ __forceinline__ f32x4 mfma16(half8 a, half8 b, f32x4 c) {
  return __builtin_amdgcn_mfma_f32_16x16x32_f16(a, b, c, 0, 0, 0);
}

__device__ __forceinline__ half8 cvt8(f32x4 a, f32x4 b) {
  half8 h;
  h[0] = (_Float16)a[0]; h[1] = (_Float16)a[1]; h[2] = (_Float16)a[2]; h[3] = (_Float16)a[3];
  h[4] = (_Float16)b[0]; h[5] = (_Float16)b[1]; h[6] = (_Float16)b[2]; h[7] = (_Float16)b[3];
  return h;
}

__device__ __forceinline__ half8 neg8(half8 a) {
  half8 r;
#pragma unroll
  for (int i = 0; i < 8; i++) r[i] = -a[i];
  return r;
}

__device__ __forceinline__ unsigned pkrtz(float a, float b) {
  return __builtin_bit_cast(unsigned, __builtin_amdgcn_cvt_pkrtz(a, b));
}

__device__ __forceinline__ float fexp2(float x) { return __builtin_amdgcn_exp2f(x); }

__device__ __forceinline__ void gload16(const void* g, void* l) {
  __builtin_amdgcn_global_load_lds((const __attribute__((address_space(1))) void*)g,
                                   (__attribute__((address_space(3))) void*)l, 16, 0, 0);
}

// ---------------- kernel 0: convert weights fp32 -> fp16 into ws ----------------
__global__ __launch_bounds__(256) void cvt_weights_kernel(
    const float* __restrict__ iwr, const float* __restrict__ iwi,
    const float* __restrict__ owr, const float* __restrict__ owi,
    _Float16* __restrict__ dst) {
  const int i = blockIdx.x * 256 + threadIdx.x;  // 262144 threads, 8 elems each
  const float* src;
  long so, doff;
  if (i < 98304)       { src = iwr; so = (long)i * 8;            doff = so; }
  else if (i < 196608) { src = iwi; so = (long)(i - 98304) * 8;  doff = 786432 + so; }
  else if (i < 229376) { src = owr; so = (long)(i - 196608) * 8; doff = 1572864 + so; }
  else                 { src = owi; so = (long)(i - 229376) * 8; doff = 1835008 + so; }
  f32x4 a = *(const f32x4*)(src + so);
  f32x4 b = *(const f32x4*)(src + so + 4);
  *(half8*)(dst + doff) = cvt8(a, b);
}

// ---------------- kernel 1: in-projection complex GEMM (reg-staged, LDS dbuf) ----------------
// 128x128 tile, BK=32, 4 waves x 64x64. A: reg-staged fp32->fp16 (write-side XOR
// swizzle). B: gload_lds pre-swizzled. Double-buffered LDS: stage(k+1) issued
// before compute(k), one barrier per K-step -> B gloads overlap the MFMA phase.
__global__ __launch_bounds__(256, 2) void inproj_kernel(
    const float* __restrict__ xqr, const float* __restrict__ xqi,
    const float* __restrict__ xkr, const float* __restrict__ xki,
    const float* __restrict__ xvr, const float* __restrict__ xvi,
    const _Float16* __restrict__ wr, const _Float16* __restrict__ wi,   // (1536,512) fp16
    const float* __restrict__ br_, const float* __restrict__ bi_,      // (1536)
    _Float16* __restrict__ qp, _Float16* __restrict__ kp,
    _Float16* __restrict__ vp) {
  __shared__ _Float16 As_r[2][4096], As_i[2][4096];    // [buf][128][32] fp16, swizzled
  __shared__ _Float16 Bs_r[2][4096], Bs_i[2][4096];    // 64 KB total -> 2 blocks/CU
  const int proj = blockIdx.z;
  const float* xr = (proj == 0) ? xqr : (proj == 1) ? xkr : xvr;
  const float* xi = (proj == 0) ? xqi : (proj == 1) ? xki : xvi;
  const int tid = threadIdx.x;
  const int lane = tid & 63, wave = tid >> 6;
  const int c = lane & 15, g = lane >> 4;
  const int wrow = (wave >> 1) * 64, wcol = (wave & 1) * 64;
  const int m0 = blockIdx.x * 128, n0 = blockIdx.y * 128;

  // --- A reg-staging geometry: thread covers row ar, col groups acg, acg+1 ---
  const int ar = tid >> 1;                  // 0..127
  const int acg = (tid & 1) * 2;            // 0 or 2
  const int aswz = (ar >> 1) & 3;           // row swizzle key
  const float* xr_st = xr + (long)(m0 + ar) * 512 + acg * 8;
  const float* xi_st = xi + (long)(m0 + ar) * 512 + acg * 8;
  const int awo0 = ar * 32 + ((acg ^ aswz) << 3);
  const int awo1 = ar * 32 + (((acg + 1) ^ aswz) << 3);

  const int bcol = ((lane & 3) ^ ((lane >> 3) & 3)) * 8;  // B staging col (lane const)
  const int sb = ((c >> 1) & 3) << 3;                     // fragment read swizzle
  const int bg0 = wave * 2, bg1 = wave * 2 + 1;
  const int brow0 = bg0 * 16 + (lane >> 2);
  const int brow1 = bg1 * 16 + (lane >> 2);
  const _Float16* wr0 = wr + (long)(proj * 512 + n0 + brow0) * 512 + bcol;
  const _Float16* wi0 = wi + (long)(proj * 512 + n0 + brow0) * 512 + bcol;
  const _Float16* wr1 = wr + (long)(proj * 512 + n0 + brow1) * 512 + bcol;
  const _Float16* wi1 = wi + (long)(proj * 512 + n0 + brow1) * 512 + bcol;

  f32x4 accR[4][4] = {};
  f32x4 accI[4][4] = {};

  // A regs for tile 0
  f32x4 r0 = *(const f32x4*)(xr_st);
  f32x4 r1 = *(const f32x4*)(xr_st + 4);
  f32x4 r2 = *(const f32x4*)(xr_st + 8);
  f32x4 r3 = *(const f32x4*)(xr_st + 12);
  f32x4 i0 = *(const f32x4*)(xi_st);
  f32x4 i1 = *(const f32x4*)(xi_st + 4);
  f32x4 i2 = *(const f32x4*)(xi_st + 8);
  f32x4 i3 = *(const f32x4*)(xi_st + 12);

  // stage tile 0 into buf 0
  *(half8*)&As_r[0][awo0] = cvt8(r0, r1);
  *(half8*)&As_r[0][awo1] = cvt8(r2, r3);
  *(half8*)&As_i[0][awo0] = cvt8(i0, i1);
  *(half8*)&As_i[0][awo1] = cvt8(i2, i3);
  gload16(wr0, &Bs_r[0][bg0 * 512]);
  gload16(wi0, &Bs_i[0][bg0 * 512]);
  gload16(wr1, &Bs_r[0][bg1 * 512]);
  gload16(wi1, &Bs_i[0][bg1 * 512]);
  // A regs for tile 1
  r0 = *(const f32x4*)(xr_st + 32);
  r1 = *(const f32x4*)(xr_st + 36);
  r2 = *(const f32x4*)(xr_st + 40);
  r3 = *(const f32x4*)(xr_st + 44);
  i0 = *(const f32x4*)(xi_st + 32);
  i1 = *(const f32x4*)(xi_st + 36);
  i2 = *(const f32x4*)(xi_st + 40);
  i3 = *(const f32x4*)(xi_st + 44);

#pragma unroll 1
  for (int k = 0; k < 16; k++) {
    const int cur = k & 1, nxt = cur ^ 1;
    __syncthreads();   // buf[cur] staged; buf[nxt] free (read out 2 steps ago)
    // ---- stage tile k+1 into buf[nxt] (gloads fly across the MFMA phase) ----
    if (k < 15) {
      const int kk1 = (k + 1) * 32;
      *(half8*)&As_r[nxt][awo0] = cvt8(r0, r1);
      *(half8*)&As_r[nxt][awo1] = cvt8(r2, r3);
      *(half8*)&As_i[nxt][awo0] = cvt8(i0, i1);
      *(half8*)&As_i[nxt][awo1] = cvt8(i2, i3);
      gload16(wr0 + kk1, &Bs_r[nxt][bg0 * 512]);
      gload16(wi0 + kk1, &Bs_i[nxt][bg0 * 512]);
      gload16(wr1 + kk1, &Bs_r[nxt][bg1 * 512]);
      gload16(wi1 + kk1, &Bs_i[nxt][bg1 * 512]);
    }
    // ---- prefetch A regs for tile k+2 ----
    if (k < 14) {
      const int kk2 = (k + 2) * 32;
      r0 = *(const f32x4*)(xr_st + kk2);
      r1 = *(const f32x4*)(xr_st + kk2 + 4);
      r2 = *(const f32x4*)(xr_st + kk2 + 8);
      r3 = *(const f32x4*)(xr_st + kk2 + 12);
      i0 = *(const f32x4*)(xi_st + kk2);
      i1 = *(const f32x4*)(xi_st + kk2 + 4);
      i2 = *(const f32x4*)(xi_st + kk2 + 8);
      i3 = *(const f32x4*)(xi_st + kk2 + 12);
    }
    // ---- compute tile k from buf[cur] ----
    half8 a_r[4], a_i[4], a_ni[4];
#pragma unroll
    for (int mt = 0; mt < 4; mt++) {
      const int arow = wrow + mt * 16 + c;
      a_r[mt] = *(const half8*)&As_r[cur][arow * 32 + ((g * 8) ^ sb)];
      a_i[mt] = *(const half8*)&As_i[cur][arow * 32 + ((g * 8) ^ sb)];
      a_ni[mt] = neg8(a_i[mt]);
    }
#pragma unroll
    for (int nt = 0; nt < 4; nt++) {
      const int brow = wcol + nt * 16 + c;
      const half8 bR = *(const half8*)&Bs_r[cur][brow * 32 + ((g * 8) ^ sb)];
      const half8 bI = *(const half8*)&Bs_i[cur][brow * 32 + ((g * 8) ^ sb)];
#pragma unroll
      for (int mt = 0; mt < 4; mt++) {
        accR[mt][nt] = mfma16(a_r[mt], bR, accR[mt][nt]);
        accR[mt][nt] = mfma16(a_ni[mt], bI, accR[mt][nt]);  // yr = xr*wr - xi*wi
        accI[mt][nt] = mfma16(a_r[mt], bI, accI[mt][nt]);
        accI[mt][nt] = mfma16(a_i[mt], bR, accI[mt][nt]);   // yi = xr*wi + xi*wr
      }
    }
  }
  // ---- epilogue: fragment-order Q/K/V writes ----
#pragma unroll
  for (int nt = 0; nt < 4; nt++) {
    const int n = n0 + wcol + nt * 16 + c;
    const float vbr = br_[proj * 512 + n];
    const float vbi = bi_[proj * 512 + n];
    const int hh = n >> 6, dl = n & 63;
#pragma unroll
    for (int mt = 0; mt < 4; mt++)
#pragma unroll
      for (int r = 0; r < 4; r++) {
        const int m = m0 + wrow + mt * 16 + g * 4 + r;
        const float yr = accR[mt][nt][r] + vbr;
        const float yi = accI[mt][nt][r] + vbi;
        const int row = m >> 2, bb = m & 3;           // m = row*B + b
        if (proj == 2) {
          const long o = ((long)((bb * 8 + hh) * 64 + (row >> 5)) << 12)
                       + ((long)(dl >> 4) << 10)
                       + ((((row >> 3) & 3) * 16 + (dl & 15)) * 8) + (row & 7);
          vp[o] = (_Float16)yr;
          vp[o + 512] = (_Float16)yi;
        } else {
          const long o = ((long)((bb * 8 + hh) * 128 + (row >> 4)) << 11)
                       + ((long)(dl >> 5) << 10)
                       + ((((dl >> 3) & 3) * 16 + (row & 15)) * 8) + (dl & 7);
          _Float16* dst = (proj == 0) ? qp : kp;
          dst[o] = (_Float16)yr;
          dst[o + 512] = (_Float16)yi;
        }
      }
  }
}

// ---------------- kernel 2: softmax pass 1 -> c = -(m + log2(l)) per row ----------------
// 256 blocks, 8 waves; each wave handles TWO t-strips against the same K buffers.
__device__ __forceinline__ void p1_load(half8 (&a)[8],
    const _Float16* kb, int s0) {
  const _Float16* p = kb + (long)(s0 >> 4) * 2048;
#pragma unroll
  for (int j = 0; j < 4; j++) {
    a[j]     = *(const half8*)(p + j * 512);
    a[4 + j] = *(const half8*)(p + 2048 + j * 512);
  }
}

__device__ __forceinline__ void p1_proc(const half8 (&a)[8], const half8 (&qf)[4],
                                        float& mrun, float& lrun) {
  const float SC2 = 0.18033688011112042f;  // log2(e)/sqrt(64)
  f32x4 acc0 = {0.f, 0.f, 0.f, 0.f}, acc1 = {0.f, 0.f, 0.f, 0.f};
  __builtin_amdgcn_s_setprio(1);
  acc0 = mfma16(a[0], qf[0], acc0);   // Re[QK^H] = qr*kr + qi*ki
  acc0 = mfma16(a[1], qf[1], acc0);
  acc0 = mfma16(a[2], qf[2], acc0);
  acc0 = mfma16(a[3], qf[3], acc0);
  acc1 = mfma16(a[4], qf[0], acc1);
  acc1 = mfma16(a[5], qf[1], acc1);
  acc1 = mfma16(a[6], qf[2], acc1);
  acc1 = mfma16(a[7], qf[3], acc1);
  __builtin_amdgcn_s_setprio(0);
  float s2[8];
#pragma unroll
  for (int r = 0; r < 4; r++) { s2[r] = acc0[r] * SC2; s2[4 + r] = acc1[r] * SC2; }
  float tm = s2[0];
#pragma unroll
  for (int j = 1; j < 8; j++) tm = fmaxf(tm, s2[j]);
  const float nm = fmaxf(mrun, tm);
  float sum = 0.0f;
#pragma unroll
  for (int j = 0; j < 8; j++) sum += fexp2(s2[j] - nm);
  lrun = lrun * fexp2(mrun - nm) + sum;
  mrun = nm;
}

__global__ __launch_bounds__(512) void pass1_kernel(
    const _Float16* __restrict__ qp, const _Float16* __restrict__ kp,
    float* __restrict__ c_out) {
  const int lane = threadIdx.x & 63, wave = threadIdx.x >> 6;
  const int c = lane & 15;
  const int lin = blockIdx.x;                  // 256 blocks
  const int h = lin & 7, b = (lin >> 3) & 3;   // (h,b) fixed per XCD (lin&7)
  const int t0 = (lin >> 5) * 256 + wave * 16; // strip0; strip1 = t0 + 128

  const _Float16* qb0 = qp + ((long)(b * 8 + h) * 128 + (t0 >> 4)) * 2048 + lane * 8;
  half8 qf0[4], qf1[4];
#pragma unroll
  for (int j = 0; j < 4; j++) {
    qf0[j] = *(const half8*)(qb0 + j * 512);
    qf1[j] = *(const half8*)(qb0 + 8 * 2048 + j * 512);   // +128 t-rows
  }

  float m0 = -1e30f, l0 = 0.0f, m1 = -1e30f, l1 = 0.0f;
  const _Float16* kb = kp + (long)(b * 8 + h) * 262144 + lane * 8;

  half8 bufA[8], bufB[8];
  p1_load(bufA, kb, 0);
  p1_load(bufB, kb, 32);
#pragma unroll 1
  for (int s0 = 0; s0 < 2048; s0 += 64) {
    p1_proc(bufA, qf0, m0, l0);
    p1_proc(bufA, qf1, m1, l1);
    p1_load(bufA, kb, (s0 + 64) & 2047);
    p1_proc(bufB, qf0, m0, l0);
    p1_proc(bufB, qf1, m1, l1);
    p1_load(bufB, kb, (s0 + 96) & 2047);
  }
#pragma unroll
  for (int off = 16; off <= 32; off <<= 1) {
    const float mo0 = __shfl_xor(m0, off, 64);
    const float lo0 = __shfl_xor(l0, off, 64);
    const float nm0 = fmaxf(m0, mo0);
    l0 = l0 * fexp2(m0 - nm0) + lo0 * fexp2(mo0 - nm0);
    m0 = nm0;
    const float mo1 = __shfl_xor(m1, off, 64);
    const float lo1 = __shfl_xor(l1, off, 64);
    const float nm1 = fmaxf(m1, mo1);
    l1 = l1 * fexp2(m1 - nm1) + lo1 * fexp2(mo1 - nm1);
    m1 = nm1;
  }
  if (lane < 16) {
    const int idx = (b * 8 + h) * 2048 + t0 + c;
    c_out[idx] = -(m0 + __log2f(l0));        // p = exp2(s*SC2 + c) is normalized
    c_out[idx + 128] = -(m1 + __log2f(l1));
  }
}

// ---------------- kernel 3: softmax pass 2 + attn mean + PV (R9 known-good) ----------------
__device__ __forceinline__ void load_kswap(half8 (&kf)[8],
    const _Float16* kb, int s) {
  const _Float16* p = kb + (long)(s >> 4) * 2048;
#pragma unroll
  for (int j = 0; j < 4; j++) {
    kf[j]     = *(const half8*)(p + j * 512);
    kf[4 + j] = *(const half8*)(p + 2048 + j * 512);
  }
}

__device__ __forceinline__ void load_vv(half8 (&vf)[8],
    const _Float16* vb, int s) {
  const _Float16* p = vb + (long)(s >> 5) * 4096;
#pragma unroll
  for (int t = 0; t < 8; t++) vf[t] = *(const half8*)(p + t * 512);
}

// compute half-step: scores -> p (in regs + LDS stash) -> PV; prefetch next K/V
__device__ __forceinline__ void p2_compute(
    int s0, _Float16* wbuf, half8 (&kf)[8], half8 (&vf)[8],
    const half8 (&qf)[8], float c0, float c1,
    f32x4 (&oacc)[2][4][2],
    const _Float16* kb, const _Float16* vb,
    int c, int g, int h) {
  const float SC2 = 0.18033688011112042f;
  f32x4 sacc[2][2];
  __builtin_amdgcn_s_setprio(1);
#pragma unroll
  for (int st = 0; st < 2; st++)
#pragma unroll
    for (int sq = 0; sq < 2; sq++) {
      f32x4 a = {0.f, 0.f, 0.f, 0.f};
      a = mfma16(kf[sq * 4 + 0], qf[st * 4 + 0], a);
      a = mfma16(kf[sq * 4 + 1], qf[st * 4 + 1], a);
      a = mfma16(kf[sq * 4 + 2], qf[st * 4 + 2], a);
      a = mfma16(kf[sq * 4 + 3], qf[st * 4 + 3], a);
      sacc[st][sq] = a;
    }
  __builtin_amdgcn_s_setprio(0);
  const int sn = (s0 + 32) & 2047;
  load_kswap(kf, kb, sn);
  half8 pa0, pa1;
#pragma unroll
  for (int st = 0; st < 2; st++) {
    const float cc = st ? c1 : c0;
    float p[8];
#pragma unroll
    for (int r = 0; r < 4; r++) {
      p[r]     = fexp2(fmaf(sacc[st][0][r], SC2, cc));  // s_local = 4g+r
      p[4 + r] = fexp2(fmaf(sacc[st][1][r], SC2, cc));  // s_local = 16+4g+r
    }
    const unsigned X0 = pkrtz(p[0], p[1]), X1 = pkrtz(p[2], p[3]);
    const unsigned Y0 = pkrtz(p[4], p[5]), Y1 = pkrtz(p[6], p[7]);
    const uint2v ab0 = __builtin_amdgcn_permlane32_swap(X0, Y0, false, false);
    const uint2v ab1 = __builtin_amdgcn_permlane32_swap(X1, Y1, false, false);
    const uint2v cd0 = __builtin_amdgcn_permlane16_swap(ab0[0], ab0[1], false, false);
    const uint2v cd1 = __builtin_amdgcn_permlane16_swap(ab1[0], ab1[1], false, false);
    uint4v u;
    u[0] = cd0[0]; u[1] = cd1[0]; u[2] = cd0[1]; u[3] = cd1[1];
    const half8 pav = __builtin_bit_cast(half8, u);   // p[t=c][s0 + g*8 .. g*8+7]
    if (st == 0) pa0 = pav; else pa1 = pav;
    *(half8*)(wbuf + (h * 32 + st * 16 + c) * 40 + g * 8) = pav;
  }
  __builtin_amdgcn_s_setprio(1);
#pragma unroll
  for (int dt = 0; dt < 4; dt++) {
    oacc[0][dt][0] = mfma16(pa0, vf[dt * 2 + 0], oacc[0][dt][0]);
    oacc[0][dt][1] = mfma16(pa0, vf[dt * 2 + 1], oacc[0][dt][1]);
    oacc[1][dt][0] = mfma16(pa1, vf[dt * 2 + 0], oacc[1][dt][0]);
    oacc[1][dt][1] = mfma16(pa1, vf[dt * 2 + 1], oacc[1][dt][1]);
  }
  __builtin_amdgcn_s_setprio(0);
  load_vv(vf, vb, sn);
}

// mean over heads of the p-tile written at step s_read (packed fp16 adds)
__device__ __forceinline__ void p2_meanread(
    const _Float16* rbuf, int s_read, float* attn_base, int tid) {
  const _Float16* mp = rbuf + (tid >> 4) * 40 + (tid & 15) * 2;
  half2v s = *(const half2v*)(mp);
#pragma unroll
  for (int w = 1; w < 8; w++) s += *(const half2v*)(mp + w * 1280);
  f32x2 out2 = {(float)s[0] * 0.125f, (float)s[1] * 0.125f};
  *(f32x2*)(attn_base + s_read) = out2;
}

__global__ __launch_bounds__(512, 2) void pass2_kernel(
    const _Float16* __restrict__ qp, const _Float16* __restrict__ kp,
    const _Float16* __restrict__ vp,
    const float* __restrict__ c_in,
    _Float16* __restrict__ orh, _Float16* __restrict__ oih,
    float* __restrict__ attn) {
  __shared__ _Float16 plds[4][8][32][40];   // 4-deep p pipeline, 80 KB
  const int tid = threadIdx.x;
  const int lane = tid & 63, h = tid >> 6;
  const int c = lane & 15, g = lane >> 4;
  // XCD-locality mapping: XCD (lin&7) hosts exactly one b; 32 t-blocks per XCD pair.
  const int lin = blockIdx.x;                       // 256 blocks, 1-D
  const int b = (lin & 7) >> 1;
  const int t0 = (((lin & 1) << 5) | (lin >> 3)) * 32;

  const _Float16* qb = qp + ((long)(b * 8 + h) * 128 + (t0 >> 4)) * 2048 + lane * 8;
  half8 qf[8];
#pragma unroll
  for (int st = 0; st < 2; st++)
#pragma unroll
    for (int j = 0; j < 4; j++)
      qf[st * 4 + j] = *(const half8*)(qb + st * 2048 + j * 512);

  const int midx = (b * 8 + h) * 2048 + t0 + c;
  const float c0 = c_in[midx];
  const float c1 = c_in[midx + 16];

  f32x4 oacc[2][4][2] = {};
  const _Float16* kb = kp + (long)(b * 8 + h) * 262144 + lane * 8;
  const _Float16* vb = vp + (long)(b * 8 + h) * 262144 + lane * 8;
  float* attn_base = attn + ((long)b * 2048 + t0 + (tid >> 4)) * 2048 + (tid & 15) * 2;
  _Float16* pb0 = &plds[0][0][0][0];
  _Float16* pb1 = &plds[1][0][0][0];
  _Float16* pb2 = &plds[2][0][0][0];
  _Float16* pb3 = &plds[3][0][0][0];

  half8 kf[8], vf[8];
  load_kswap(kf, kb, 0);
  load_vv(vf, vb, 0);

#pragma unroll 1
  for (int s0 = 0; s0 < 2048; s0 += 128) {
    // phase 0: write pb0, read pb3 (step s0-32)
    p2_compute(s0, pb0, kf, vf, qf, c0, c1, oacc, kb, vb, c, g, h);
    __syncthreads();
    if (s0 >= 32) p2_meanread(pb3, s0 - 32, attn_base, tid);
    // phase 1
    p2_compute(s0 + 32, pb1, kf, vf, qf, c0, c1, oacc, kb, vb, c, g, h);
    __syncthreads();
    p2_meanread(pb0, s0, attn_base, tid);
    // phase 2
    p2_compute(s0 + 64, pb2, kf, vf, qf, c0, c1, oacc, kb, vb, c, g, h);
    __syncthreads();
    p2_meanread(pb1, s0 + 32, attn_base, tid);
    // phase 3
    p2_compute(s0 + 96, pb3, kf, vf, qf, c0, c1, oacc, kb, vb, c, g, h);
    __syncthreads();
    p2_meanread(pb2, s0 + 64, attn_base, tid);
  }
  // drain: step 2016 sits in pb3, all writes are past the last barrier
  p2_meanread(pb3, 2016, attn_base, tid);

  // ---- epilogue: write attention output (fp16, (T*B, E) rows) ----
#pragma unroll
  for (int st = 0; st < 2; st++)
#pragma unroll
    for (int dt = 0; dt < 4; dt++)
#pragma unroll
      for (int r = 0; r < 4; r++) {
        const int t = t0 + st * 16 + g * 4 + r;
        const long row = (long)(t * 4 + b) * 512 + h * 64 + dt * 16 + c;
        orh[row] = (_Float16)oacc[st][dt][0][r];
        oih[row] = (_Float16)oacc[st][dt][1][r];
      }
}

// ---------------- kernel 4: out-projection complex GEMM ----------------
// 64x128 tiles, grid (128,4) = 512 blocks = 2/CU. 4 waves x 32x64 output.
__global__ __launch_bounds__(256, 4) void outproj_kernel(
    const _Float16* __restrict__ xr, const _Float16* __restrict__ xi,   // (8192,512)
    const _Float16* __restrict__ wr, const _Float16* __restrict__ wi,   // (512,512)
    const float* __restrict__ br_, const float* __restrict__ bi_,
    float* __restrict__ outr, float* __restrict__ outi) {
  __shared__ _Float16 As_r[2048], As_i[2048];    // [64][32] f16, swizzled
  __shared__ _Float16 Bs_r[4096], Bs_i[4096];    // [128][32] f16, swizzled
  const int lane = threadIdx.x & 63, wave = threadIdx.x >> 6;
  const int c = lane & 15, g = lane >> 4;
  const int wrow = (wave >> 1) * 32, wcol = (wave & 1) * 64;
  const int m0 = blockIdx.x * 64, n0 = blockIdx.y * 128;

  const int bcol = ((lane & 3) ^ ((lane >> 3) & 3)) * 8;  // f16 staging col (lane const)
  const int sb = ((c >> 1) & 3) << 3;                     // f16 read swizzle

  f32x4 accR[2][4] = {};
  f32x4 accI[2][4] = {};

#pragma unroll 1
  for (int kk = 0; kk < 512; kk += 32) {
    {
      const int row = wave * 16 + (lane >> 2);
      const long ga = (long)(m0 + row) * 512 + kk + bcol;
      gload16(xr + ga, &As_r[wave * 512]);
      gload16(xi + ga, &As_i[wave * 512]);
    }
#pragma unroll
    for (int q = 0; q < 2; q++) {
      const int grp = wave * 2 + q;
      const int row = grp * 16 + (lane >> 2);
      const long gb = (long)(n0 + row) * 512 + kk + bcol;
      gload16(wr + gb, &Bs_r[grp * 512]);
      gload16(wi + gb, &Bs_i[grp * 512]);
    }
    __syncthreads();
    half8 a_r[2], a_i[2], a_ni[2];
#pragma unroll
    for (int mt = 0; mt < 2; mt++) {
      const int arow = wrow + mt * 16 + c;
      a_r[mt] = *(const half8*)&As_r[arow * 32 + ((g * 8) ^ sb)];
      a_i[mt] = *(const half8*)&As_i[arow * 32 + ((g * 8) ^ sb)];
      a_ni[mt] = neg8(a_i[mt]);
    }
#pragma unroll
    for (int nt = 0; nt < 4; nt++) {
      const int brow = wcol + nt * 16 + c;
      const half8 bR = *(const half8*)&Bs_r[brow * 32 + ((g * 8) ^ sb)];
      const half8 bI = *(const half8*)&Bs_i[brow * 32 + ((g * 8) ^ sb)];
#pragma unroll
      for (int mt = 0; mt < 2; mt++) {
        accR[mt][nt] = mfma16(a_r[mt], bR, accR[mt][nt]);
        accR[mt][nt] = mfma16(a_ni[mt], bI, accR[mt][nt]);
        accI[mt][nt] = mfma16(a_r[mt], bI, accI[mt][nt]);
        accI[mt][nt] = mfma16(a_i[mt], bR, accI[mt][nt]);
      }
    }
    __syncthreads();
  }
#pragma unroll
  for (int nt = 0; nt < 4; nt++) {
    const int n = n0 + wcol + nt * 16 + c;
    const float vbr = br_[n], vbi = bi_[n];
#pragma unroll
    for (int mt = 0; mt < 2; mt++)
#pragma unroll
      for (int r = 0; r < 4; r++) {
        const int m = m0 + wrow + mt * 16 + g * 4 + r;
        outr[(long)m * 512 + n] = accR[mt][nt][r] + vbr;
        outi[(long)m * 512 + n] = accI[mt][nt][r] + vbi;
      }
  }
}

extern "C" void kernel_launch(void* const* d_in, const int* in_sizes, int n_in,
                              void* d_out, int out_size, void* d_ws, size_t ws_size,
                              hipStream_t stream) {
  const float* query_r = (const float*)d_in[0];
  const float* query_i = (const float*)d_in[1];
  const float* key_r   = (const float*)d_in[2];
  const float* key_i   = (const float*)d_in[3];
  const float* value_r = (const float*)d_in[4];
  const float* value_i = (const float*)d_in[5];
  const float* in_w_r  = (const float*)d_in[6];
  const float* in_w_i  = (const float*)d_in[7];
  const float* in_b_r  = (const float*)d_in[8];
  const float* in_b_i  = (const float*)d_in[9];
  const float* out_w_r = (const float*)d_in[10];
  const float* out_w_i = (const float*)d_in[11];
  const float* out_b_r = (const float*)d_in[12];
  const float* out_b_i = (const float*)d_in[13];

  // workspace layout (fp16 elements), total 71,827,456 B
  _Float16* ws = (_Float16*)d_ws;
  _Float16* w16_inr  = ws;                   // 786432   (dead after inproj)
  _Float16* w16_ini  = ws + 786432;          // 786432
  _Float16* w16_outr = ws + 1572864;         // 262144
  _Float16* w16_outi = ws + 1835008;         // 262144
  _Float16* Qp  = ws + 2097152;              // 8388608  (fragment-order)
  _Float16* Kp  = Qp + 8388608;              // 8388608
  _Float16* Vp  = Kp + 8388608;              // 8388608
  _Float16* orh = Vp + 8388608;              // 4194304
  _Float16* oih = orh + 4194304;             // 4194304
  // c overlays the dead in-proj weight region (pass1 runs after inproj)
  float* c_arr = (float*)ws;                 // 65536 fp32

  float* outr = (float*)d_out;               // (T,B,E)
  float* outi = outr + 4194304;              // (T,B,E)
  float* attn = outr + 8388608;              // (B,T,S)

  cvt_weights_kernel<<<1024, 256, 0, stream>>>(in_w_r, in_w_i, out_w_r, out_w_i, ws);

  inproj_kernel<<<dim3(64, 4, 3), 256, 0, stream>>>(
      query_r, query_i, key_r, key_i, value_r, value_i,
      w16_inr, w16_ini, in_b_r, in_b_i,
      Qp, Kp, Vp);

  pass1_kernel<<<256, 512, 0, stream>>>(Qp, Kp, c_arr);

  pass2_kernel<<<256, 512, 0, stream>>>(
      Qp, Kp, Vp, c_arr, orh, oih, attn);

  outproj_kernel<<<dim3(128, 4), 256, 0, stream>>>(
      orh, oih, w16_outr, w16_outi, out_b_r, out_b_i, outr, outi);
}

// Round 14
// 244.235 us; speedup vs baseline: 1.0449x; 1.0449x over previous
//
#include <hip/hip_runtime.h>

// Complex MultiheadAttention, fp16-MFMA implementation for gfx950.
// E=512 H=8 D=64 T=S=2048 B=4. All shapes divide tile sizes exactly.
// Q/K/V stored in MFMA-fragment order (1KB contiguous per wave load).
// pass2: R9 known-good (512 thr, QBLK=32, 4-deep LDS p-pipeline, folded norm).
//        QBLK=64 register-infeasible; QBLK=16 exceeds per-XCD L2 BW; s-split
//        needs workspace beyond known-safe 72MB. Structural plateau ~106 us.
// pass1: 2 t-strips per wave -> K traffic halved (256 blocks).
// inproj: R7/R12 reg-staged, 2-barrier (best of 3 structures tried; dbuf and
//         8-wave variants both regressed).
// outproj: 64x128 tiles, 512 blocks = 2/CU.

typedef _Float16 half8 __attribute__((ext_vector_type(8)));
typedef _Float16 half2v __attribute__((ext_vector_type(2)));
typedef float f32x4 __attribute__((ext_vector_type(4)));
typedef float f32x2 __attribute__((ext_vector_type(2)));
typedef unsigned uint2v __attribute__((ext_vector_type(2)));
typedef unsigned uint4v __attribute__((ext_vector_type(4)));

__device__ __forceinline__ f32x4 mfma16(half8 a, half8 b, f32x4 c) {
  return __builtin_amdgcn_mfma_f32_16x16x32_f16(a, b, c, 0, 0, 0);
}

__device__ __forceinline__ half8 cvt8(f32x4 a, f32x4 b) {
  half8 h;
  h[0] = (_Float16)a[0]; h[1] = (_Float16)a[1]; h[2] = (_Float16)a[2]; h[3] = (_Float16)a[3];
  h[4] = (_Float16)b[0]; h[5] = (_Float16)b[1]; h[6] = (_Float16)b[2]; h[7] = (_Float16)b[3];
  return h;
}

__device__ __forceinline__ half8 neg8(half8 a) {
  half8 r;
#pragma unroll
  for (int i = 0; i < 8; i++) r[i] = -a[i];
  return r;
}

__device__ __forceinline__ unsigned pkrtz(float a, float b) {
  return __builtin_bit_cast(unsigned, __builtin_amdgcn_cvt_pkrtz(a, b));
}

__device__ __forceinline__ float fexp2(float x) { return __builtin_amdgcn_exp2f(x); }

__device__ __forceinline__ void gload16(const void* g, void* l) {
  __builtin_amdgcn_global_load_lds((const __attribute__((address_space(1))) void*)g,
                                   (__attribute__((address_space(3))) void*)l, 16, 0, 0);
}

// ---------------- kernel 0: convert weights fp32 -> fp16 into ws ----------------
__global__ __launch_bounds__(256) void cvt_weights_kernel(
    const float* __restrict__ iwr, const float* __restrict__ iwi,
    const float* __restrict__ owr, const float* __restrict__ owi,
    _Float16* __restrict__ dst) {
  const int i = blockIdx.x * 256 + threadIdx.x;  // 262144 threads, 8 elems each
  const float* src;
  long so, doff;
  if (i < 98304)       { src = iwr; so = (long)i * 8;            doff = so; }
  else if (i < 196608) { src = iwi; so = (long)(i - 98304) * 8;  doff = 786432 + so; }
  else if (i < 229376) { src = owr; so = (long)(i - 196608) * 8; doff = 1572864 + so; }
  else                 { src = owi; so = (long)(i - 229376) * 8; doff = 1835008 + so; }
  f32x4 a = *(const f32x4*)(src + so);
  f32x4 b = *(const f32x4*)(src + so + 4);
  *(half8*)(dst + doff) = cvt8(a, b);
}

// ---------------- kernel 1: in-projection complex GEMM (R7 reg-staged) ----------------
__global__ __launch_bounds__(256, 2) void inproj_kernel(
    const float* __restrict__ xqr, const float* __restrict__ xqi,
    const float* __restrict__ xkr, const float* __restrict__ xki,
    const float* __restrict__ xvr, const float* __restrict__ xvi,
    const _Float16* __restrict__ wr, const _Float16* __restrict__ wi,   // (1536,512) fp16
    const float* __restrict__ br_, const float* __restrict__ bi_,      // (1536)
    _Float16* __restrict__ qp, _Float16* __restrict__ kp,
    _Float16* __restrict__ vp) {
  __shared__ _Float16 As_r[4096], As_i[4096];    // [128][32] fp16, swizzled
  __shared__ _Float16 Bs_r[4096], Bs_i[4096];    // [128][32] fp16, swizzled
  const int proj = blockIdx.z;
  const float* xr = (proj == 0) ? xqr : (proj == 1) ? xkr : xvr;
  const float* xi = (proj == 0) ? xqi : (proj == 1) ? xki : xvi;
  const int tid = threadIdx.x;
  const int lane = tid & 63, wave = tid >> 6;
  const int c = lane & 15, g = lane >> 4;
  const int wrow = (wave >> 1) * 64, wcol = (wave & 1) * 64;
  const int m0 = blockIdx.x * 128, n0 = blockIdx.y * 128;

  const int ar = tid >> 1;                  // 0..127
  const int acg = (tid & 1) * 2;            // 0 or 2
  const int aswz = (ar >> 1) & 3;           // row swizzle key
  const float* xr_st = xr + (long)(m0 + ar) * 512 + acg * 8;
  const float* xi_st = xi + (long)(m0 + ar) * 512 + acg * 8;
  _Float16* aw_r0 = &As_r[ar * 32 + ((acg ^ aswz) << 3)];
  _Float16* aw_r1 = &As_r[ar * 32 + (((acg + 1) ^ aswz) << 3)];
  _Float16* aw_i0 = &As_i[ar * 32 + ((acg ^ aswz) << 3)];
  _Float16* aw_i1 = &As_i[ar * 32 + (((acg + 1) ^ aswz) << 3)];

  const int bcol = ((lane & 3) ^ ((lane >> 3) & 3)) * 8;  // B staging col (lane const)
  const int sb = ((c >> 1) & 3) << 3;                     // fragment read swizzle

  f32x4 accR[4][4] = {};
  f32x4 accI[4][4] = {};

  f32x4 r0 = *(const f32x4*)(xr_st);
  f32x4 r1 = *(const f32x4*)(xr_st + 4);
  f32x4 r2 = *(const f32x4*)(xr_st + 8);
  f32x4 r3 = *(const f32x4*)(xr_st + 12);
  f32x4 i0 = *(const f32x4*)(xi_st);
  f32x4 i1 = *(const f32x4*)(xi_st + 4);
  f32x4 i2 = *(const f32x4*)(xi_st + 8);
  f32x4 i3 = *(const f32x4*)(xi_st + 12);

#pragma unroll 1
  for (int kk = 0; kk < 512; kk += 32) {
    *(half8*)aw_r0 = cvt8(r0, r1);
    *(half8*)aw_r1 = cvt8(r2, r3);
    *(half8*)aw_i0 = cvt8(i0, i1);
    *(half8*)aw_i1 = cvt8(i2, i3);
#pragma unroll
    for (int q = 0; q < 2; q++) {
      const int grp = wave * 2 + q;
      const int brow = grp * 16 + (lane >> 2);
      const long go = (long)(proj * 512 + n0 + brow) * 512 + kk + bcol;
      gload16(wr + go, &Bs_r[grp * 512]);
      gload16(wi + go, &Bs_i[grp * 512]);
    }
    __syncthreads();
    if (kk < 480) {
      r0 = *(const f32x4*)(xr_st + kk + 32);
      r1 = *(const f32x4*)(xr_st + kk + 36);
      r2 = *(const f32x4*)(xr_st + kk + 40);
      r3 = *(const f32x4*)(xr_st + kk + 44);
      i0 = *(const f32x4*)(xi_st + kk + 32);
      i1 = *(const f32x4*)(xi_st + kk + 36);
      i2 = *(const f32x4*)(xi_st + kk + 40);
      i3 = *(const f32x4*)(xi_st + kk + 44);
    }
    half8 a_r[4], a_i[4], a_ni[4];
#pragma unroll
    for (int mt = 0; mt < 4; mt++) {
      const int arow = wrow + mt * 16 + c;
      a_r[mt] = *(const half8*)&As_r[arow * 32 + ((g * 8) ^ sb)];
      a_i[mt] = *(const half8*)&As_i[arow * 32 + ((g * 8) ^ sb)];
      a_ni[mt] = neg8(a_i[mt]);
    }
#pragma unroll
    for (int nt = 0; nt < 4; nt++) {
      const int brow = wcol + nt * 16 + c;
      const half8 bR = *(const half8*)&Bs_r[brow * 32 + ((g * 8) ^ sb)];
      const half8 bI = *(const half8*)&Bs_i[brow * 32 + ((g * 8) ^ sb)];
#pragma unroll
      for (int mt = 0; mt < 4; mt++) {
        accR[mt][nt] = mfma16(a_r[mt], bR, accR[mt][nt]);
        accR[mt][nt] = mfma16(a_ni[mt], bI, accR[mt][nt]);  // yr = xr*wr - xi*wi
        accI[mt][nt] = mfma16(a_r[mt], bI, accI[mt][nt]);
        accI[mt][nt] = mfma16(a_i[mt], bR, accI[mt][nt]);   // yi = xr*wi + xi*wr
      }
    }
    __syncthreads();
  }
#pragma unroll
  for (int nt = 0; nt < 4; nt++) {
    const int n = n0 + wcol + nt * 16 + c;
    const float vbr = br_[proj * 512 + n];
    const float vbi = bi_[proj * 512 + n];
    const int hh = n >> 6, dl = n & 63;
#pragma unroll
    for (int mt = 0; mt < 4; mt++)
#pragma unroll
      for (int r = 0; r < 4; r++) {
        const int m = m0 + wrow + mt * 16 + g * 4 + r;
        const float yr = accR[mt][nt][r] + vbr;
        const float yi = accI[mt][nt][r] + vbi;
        const int row = m >> 2, bb = m & 3;           // m = row*B + b
        if (proj == 2) {
          const long o = ((long)((bb * 8 + hh) * 64 + (row >> 5)) << 12)
                       + ((long)(dl >> 4) << 10)
                       + ((((row >> 3) & 3) * 16 + (dl & 15)) * 8) + (row & 7);
          vp[o] = (_Float16)yr;
          vp[o + 512] = (_Float16)yi;
        } else {
          const long o = ((long)((bb * 8 + hh) * 128 + (row >> 4)) << 11)
                       + ((long)(dl >> 5) << 10)
                       + ((((dl >> 3) & 3) * 16 + (row & 15)) * 8) + (dl & 7);
          _Float16* dst = (proj == 0) ? qp : kp;
          dst[o] = (_Float16)yr;
          dst[o + 512] = (_Float16)yi;
        }
      }
  }
}

// ---------------- kernel 2: softmax pass 1 -> c = -(m + log2(l)) per row ----------------
// 256 blocks, 8 waves; each wave handles TWO t-strips against the same K buffers.
__device__ __forceinline__ void p1_load(half8 (&a)[8],
    const _Float16* kb, int s0) {
  const _Float16* p = kb + (long)(s0 >> 4) * 2048;
#pragma unroll
  for (int j = 0; j < 4; j++) {
    a[j]     = *(const half8*)(p + j * 512);
    a[4 + j] = *(const half8*)(p + 2048 + j * 512);
  }
}

__device__ __forceinline__ void p1_proc(const half8 (&a)[8], const half8 (&qf)[4],
                                        float& mrun, float& lrun) {
  const float SC2 = 0.18033688011112042f;  // log2(e)/sqrt(64)
  f32x4 acc0 = {0.f, 0.f, 0.f, 0.f}, acc1 = {0.f, 0.f, 0.f, 0.f};
  __builtin_amdgcn_s_setprio(1);
  acc0 = mfma16(a[0], qf[0], acc0);   // Re[QK^H] = qr*kr + qi*ki
  acc0 = mfma16(a[1], qf[1], acc0);
  acc0 = mfma16(a[2], qf[2], acc0);
  acc0 = mfma16(a[3], qf[3], acc0);
  acc1 = mfma16(a[4], qf[0], acc1);
  acc1 = mfma16(a[5], qf[1], acc1);
  acc1 = mfma16(a[6], qf[2], acc1);
  acc1 = mfma16(a[7], qf[3], acc1);
  __builtin_amdgcn_s_setprio(0);
  float s2[8];
#pragma unroll
  for (int r = 0; r < 4; r++) { s2[r] = acc0[r] * SC2; s2[4 + r] = acc1[r] * SC2; }
  float tm = s2[0];
#pragma unroll
  for (int j = 1; j < 8; j++) tm = fmaxf(tm, s2[j]);
  const float nm = fmaxf(mrun, tm);
  float sum = 0.0f;
#pragma unroll
  for (int j = 0; j < 8; j++) sum += fexp2(s2[j] - nm);
  lrun = lrun * fexp2(mrun - nm) + sum;
  mrun = nm;
}

__global__ __launch_bounds__(512) void pass1_kernel(
    const _Float16* __restrict__ qp, const _Float16* __restrict__ kp,
    float* __restrict__ c_out) {
  const int lane = threadIdx.x & 63, wave = threadIdx.x >> 6;
  const int c = lane & 15;
  const int lin = blockIdx.x;                  // 256 blocks
  const int h = lin & 7, b = (lin >> 3) & 3;   // (h,b) fixed per XCD (lin&7)
  const int t0 = (lin >> 5) * 256 + wave * 16; // strip0; strip1 = t0 + 128

  const _Float16* qb0 = qp + ((long)(b * 8 + h) * 128 + (t0 >> 4)) * 2048 + lane * 8;
  half8 qf0[4], qf1[4];
#pragma unroll
  for (int j = 0; j < 4; j++) {
    qf0[j] = *(const half8*)(qb0 + j * 512);
    qf1[j] = *(const half8*)(qb0 + 8 * 2048 + j * 512);   // +128 t-rows
  }

  float m0 = -1e30f, l0 = 0.0f, m1 = -1e30f, l1 = 0.0f;
  const _Float16* kb = kp + (long)(b * 8 + h) * 262144 + lane * 8;

  half8 bufA[8], bufB[8];
  p1_load(bufA, kb, 0);
  p1_load(bufB, kb, 32);
#pragma unroll 1
  for (int s0 = 0; s0 < 2048; s0 += 64) {
    p1_proc(bufA, qf0, m0, l0);
    p1_proc(bufA, qf1, m1, l1);
    p1_load(bufA, kb, (s0 + 64) & 2047);
    p1_proc(bufB, qf0, m0, l0);
    p1_proc(bufB, qf1, m1, l1);
    p1_load(bufB, kb, (s0 + 96) & 2047);
  }
#pragma unroll
  for (int off = 16; off <= 32; off <<= 1) {
    const float mo0 = __shfl_xor(m0, off, 64);
    const float lo0 = __shfl_xor(l0, off, 64);
    const float nm0 = fmaxf(m0, mo0);
    l0 = l0 * fexp2(m0 - nm0) + lo0 * fexp2(mo0 - nm0);
    m0 = nm0;
    const float mo1 = __shfl_xor(m1, off, 64);
    const float lo1 = __shfl_xor(l1, off, 64);
    const float nm1 = fmaxf(m1, mo1);
    l1 = l1 * fexp2(m1 - nm1) + lo1 * fexp2(mo1 - nm1);
    m1 = nm1;
  }
  if (lane < 16) {
    const int idx = (b * 8 + h) * 2048 + t0 + c;
    c_out[idx] = -(m0 + __log2f(l0));        // p = exp2(s*SC2 + c) is normalized
    c_out[idx + 128] = -(m1 + __log2f(l1));
  }
}

// ---------------- kernel 3: softmax pass 2 + attn mean + PV (R9 known-good) ----------------
__device__ __forceinline__ void load_kswap(half8 (&kf)[8],
    const _Float16* kb, int s) {
  const _Float16* p = kb + (long)(s >> 4) * 2048;
#pragma unroll
  for (int j = 0; j < 4; j++) {
    kf[j]     = *(const half8*)(p + j * 512);
    kf[4 + j] = *(const half8*)(p + 2048 + j * 512);
  }
}

__device__ __forceinline__ void load_vv(half8 (&vf)[8],
    const _Float16* vb, int s) {
  const _Float16* p = vb + (long)(s >> 5) * 4096;
#pragma unroll
  for (int t = 0; t < 8; t++) vf[t] = *(const half8*)(p + t * 512);
}

// compute half-step: scores -> p (in regs + LDS stash) -> PV; prefetch next K/V
__device__ __forceinline__ void p2_compute(
    int s0, _Float16* wbuf, half8 (&kf)[8], half8 (&vf)[8],
    const half8 (&qf)[8], float c0, float c1,
    f32x4 (&oacc)[2][4][2],
    const _Float16* kb, const _Float16* vb,
    int c, int g, int h) {
  const float SC2 = 0.18033688011112042f;
  f32x4 sacc[2][2];
  __builtin_amdgcn_s_setprio(1);
#pragma unroll
  for (int st = 0; st < 2; st++)
#pragma unroll
    for (int sq = 0; sq < 2; sq++) {
      f32x4 a = {0.f, 0.f, 0.f, 0.f};
      a = mfma16(kf[sq * 4 + 0], qf[st * 4 + 0], a);
      a = mfma16(kf[sq * 4 + 1], qf[st * 4 + 1], a);
      a = mfma16(kf[sq * 4 + 2], qf[st * 4 + 2], a);
      a = mfma16(kf[sq * 4 + 3], qf[st * 4 + 3], a);
      sacc[st][sq] = a;
    }
  __builtin_amdgcn_s_setprio(0);
  const int sn = (s0 + 32) & 2047;
  load_kswap(kf, kb, sn);
  half8 pa0, pa1;
#pragma unroll
  for (int st = 0; st < 2; st++) {
    const float cc = st ? c1 : c0;
    float p[8];
#pragma unroll
    for (int r = 0; r < 4; r++) {
      p[r]     = fexp2(fmaf(sacc[st][0][r], SC2, cc));  // s_local = 4g+r
      p[4 + r] = fexp2(fmaf(sacc[st][1][r], SC2, cc));  // s_local = 16+4g+r
    }
    const unsigned X0 = pkrtz(p[0], p[1]), X1 = pkrtz(p[2], p[3]);
    const unsigned Y0 = pkrtz(p[4], p[5]), Y1 = pkrtz(p[6], p[7]);
    const uint2v ab0 = __builtin_amdgcn_permlane32_swap(X0, Y0, false, false);
    const uint2v ab1 = __builtin_amdgcn_permlane32_swap(X1, Y1, false, false);
    const uint2v cd0 = __builtin_amdgcn_permlane16_swap(ab0[0], ab0[1], false, false);
    const uint2v cd1 = __builtin_amdgcn_permlane16_swap(ab1[0], ab1[1], false, false);
    uint4v u;
    u[0] = cd0[0]; u[1] = cd1[0]; u[2] = cd0[1]; u[3] = cd1[1];
    const half8 pav = __builtin_bit_cast(half8, u);   // p[t=c][s0 + g*8 .. g*8+7]
    if (st == 0) pa0 = pav; else pa1 = pav;
    *(half8*)(wbuf + (h * 32 + st * 16 + c) * 40 + g * 8) = pav;
  }
  __builtin_amdgcn_s_setprio(1);
#pragma unroll
  for (int dt = 0; dt < 4; dt++) {
    oacc[0][dt][0] = mfma16(pa0, vf[dt * 2 + 0], oacc[0][dt][0]);
    oacc[0][dt][1] = mfma16(pa0, vf[dt * 2 + 1], oacc[0][dt][1]);
    oacc[1][dt][0] = mfma16(pa1, vf[dt * 2 + 0], oacc[1][dt][0]);
    oacc[1][dt][1] = mfma16(pa1, vf[dt * 2 + 1], oacc[1][dt][1]);
  }
  __builtin_amdgcn_s_setprio(0);
  load_vv(vf, vb, sn);
}

// mean over heads of the p-tile written at step s_read (packed fp16 adds)
__device__ __forceinline__ void p2_meanread(
    const _Float16* rbuf, int s_read, float* attn_base, int tid) {
  const _Float16* mp = rbuf + (tid >> 4) * 40 + (tid & 15) * 2;
  half2v s = *(const half2v*)(mp);
#pragma unroll
  for (int w = 1; w < 8; w++) s += *(const half2v*)(mp + w * 1280);
  f32x2 out2 = {(float)s[0] * 0.125f, (float)s[1] * 0.125f};
  *(f32x2*)(attn_base + s_read) = out2;
}

__global__ __launch_bounds__(512, 2) void pass2_kernel(
    const _Float16* __restrict__ qp, const _Float16* __restrict__ kp,
    const _Float16* __restrict__ vp,
    const float* __restrict__ c_in,
    _Float16* __restrict__ orh, _Float16* __restrict__ oih,
    float* __restrict__ attn) {
  __shared__ _Float16 plds[4][8][32][40];   // 4-deep p pipeline, 80 KB
  const int tid = threadIdx.x;
  const int lane = tid & 63, h = tid >> 6;
  const int c = lane & 15, g = lane >> 4;
  // XCD-locality mapping: XCD (lin&7) hosts exactly one b; 32 t-blocks per XCD pair.
  const int lin = blockIdx.x;                       // 256 blocks, 1-D
  const int b = (lin & 7) >> 1;
  const int t0 = (((lin & 1) << 5) | (lin >> 3)) * 32;

  const _Float16* qb = qp + ((long)(b * 8 + h) * 128 + (t0 >> 4)) * 2048 + lane * 8;
  half8 qf[8];
#pragma unroll
  for (int st = 0; st < 2; st++)
#pragma unroll
    for (int j = 0; j < 4; j++)
      qf[st * 4 + j] = *(const half8*)(qb + st * 2048 + j * 512);

  const int midx = (b * 8 + h) * 2048 + t0 + c;
  const float c0 = c_in[midx];
  const float c1 = c_in[midx + 16];

  f32x4 oacc[2][4][2] = {};
  const _Float16* kb = kp + (long)(b * 8 + h) * 262144 + lane * 8;
  const _Float16* vb = vp + (long)(b * 8 + h) * 262144 + lane * 8;
  float* attn_base = attn + ((long)b * 2048 + t0 + (tid >> 4)) * 2048 + (tid & 15) * 2;
  _Float16* pb0 = &plds[0][0][0][0];
  _Float16* pb1 = &plds[1][0][0][0];
  _Float16* pb2 = &plds[2][0][0][0];
  _Float16* pb3 = &plds[3][0][0][0];

  half8 kf[8], vf[8];
  load_kswap(kf, kb, 0);
  load_vv(vf, vb, 0);

#pragma unroll 1
  for (int s0 = 0; s0 < 2048; s0 += 128) {
    // phase 0: write pb0, read pb3 (step s0-32)
    p2_compute(s0, pb0, kf, vf, qf, c0, c1, oacc, kb, vb, c, g, h);
    __syncthreads();
    if (s0 >= 32) p2_meanread(pb3, s0 - 32, attn_base, tid);
    // phase 1
    p2_compute(s0 + 32, pb1, kf, vf, qf, c0, c1, oacc, kb, vb, c, g, h);
    __syncthreads();
    p2_meanread(pb0, s0, attn_base, tid);
    // phase 2
    p2_compute(s0 + 64, pb2, kf, vf, qf, c0, c1, oacc, kb, vb, c, g, h);
    __syncthreads();
    p2_meanread(pb1, s0 + 32, attn_base, tid);
    // phase 3
    p2_compute(s0 + 96, pb3, kf, vf, qf, c0, c1, oacc, kb, vb, c, g, h);
    __syncthreads();
    p2_meanread(pb2, s0 + 64, attn_base, tid);
  }
  // drain: step 2016 sits in pb3, all writes are past the last barrier
  p2_meanread(pb3, 2016, attn_base, tid);

  // ---- epilogue: write attention output (fp16, (T*B, E) rows) ----
#pragma unroll
  for (int st = 0; st < 2; st++)
#pragma unroll
    for (int dt = 0; dt < 4; dt++)
#pragma unroll
      for (int r = 0; r < 4; r++) {
        const int t = t0 + st * 16 + g * 4 + r;
        const long row = (long)(t * 4 + b) * 512 + h * 64 + dt * 16 + c;
        orh[row] = (_Float16)oacc[st][dt][0][r];
        oih[row] = (_Float16)oacc[st][dt][1][r];
      }
}

// ---------------- kernel 4: out-projection complex GEMM ----------------
// 64x128 tiles, grid (128,4) = 512 blocks = 2/CU. 4 waves x 32x64 output.
__global__ __launch_bounds__(256, 4) void outproj_kernel(
    const _Float16* __restrict__ xr, const _Float16* __restrict__ xi,   // (8192,512)
    const _Float16* __restrict__ wr, const _Float16* __restrict__ wi,   // (512,512)
    const float* __restrict__ br_, const float* __restrict__ bi_,
    float* __restrict__ outr, float* __restrict__ outi) {
  __shared__ _Float16 As_r[2048], As_i[2048];    // [64][32] f16, swizzled
  __shared__ _Float16 Bs_r[4096], Bs_i[4096];    // [128][32] f16, swizzled
  const int lane = threadIdx.x & 63, wave = threadIdx.x >> 6;
  const int c = lane & 15, g = lane >> 4;
  const int wrow = (wave >> 1) * 32, wcol = (wave & 1) * 64;
  const int m0 = blockIdx.x * 64, n0 = blockIdx.y * 128;

  const int bcol = ((lane & 3) ^ ((lane >> 3) & 3)) * 8;  // f16 staging col (lane const)
  const int sb = ((c >> 1) & 3) << 3;                     // f16 read swizzle

  f32x4 accR[2][4] = {};
  f32x4 accI[2][4] = {};

#pragma unroll 1
  for (int kk = 0; kk < 512; kk += 32) {
    {
      const int row = wave * 16 + (lane >> 2);
      const long ga = (long)(m0 + row) * 512 + kk + bcol;
      gload16(xr + ga, &As_r[wave * 512]);
      gload16(xi + ga, &As_i[wave * 512]);
    }
#pragma unroll
    for (int q = 0; q < 2; q++) {
      const int grp = wave * 2 + q;
      const int row = grp * 16 + (lane >> 2);
      const long gb = (long)(n0 + row) * 512 + kk + bcol;
      gload16(wr + gb, &Bs_r[grp * 512]);
      gload16(wi + gb, &Bs_i[grp * 512]);
    }
    __syncthreads();
    half8 a_r[2], a_i[2], a_ni[2];
#pragma unroll
    for (int mt = 0; mt < 2; mt++) {
      const int arow = wrow + mt * 16 + c;
      a_r[mt] = *(const half8*)&As_r[arow * 32 + ((g * 8) ^ sb)];
      a_i[mt] = *(const half8*)&As_i[arow * 32 + ((g * 8) ^ sb)];
      a_ni[mt] = neg8(a_i[mt]);
    }
#pragma unroll
    for (int nt = 0; nt < 4; nt++) {
      const int brow = wcol + nt * 16 + c;
      const half8 bR = *(const half8*)&Bs_r[brow * 32 + ((g * 8) ^ sb)];
      const half8 bI = *(const half8*)&Bs_i[brow * 32 + ((g * 8) ^ sb)];
#pragma unroll
      for (int mt = 0; mt < 2; mt++) {
        accR[mt][nt] = mfma16(a_r[mt], bR, accR[mt][nt]);
        accR[mt][nt] = mfma16(a_ni[mt], bI, accR[mt][nt]);
        accI[mt][nt] = mfma16(a_r[mt], bI, accI[mt][nt]);
        accI[mt][nt] = mfma16(a_i[mt], bR, accI[mt][nt]);
      }
    }
    __syncthreads();
  }
#pragma unroll
  for (int nt = 0; nt < 4; nt++) {
    const int n = n0 + wcol + nt * 16 + c;
    const float vbr = br_[n], vbi = bi_[n];
#pragma unroll
    for (int mt = 0; mt < 2; mt++)
#pragma unroll
      for (int r = 0; r < 4; r++) {
        const int m = m0 + wrow + mt * 16 + g * 4 + r;
        outr[(long)m * 512 + n] = accR[mt][nt][r] + vbr;
        outi[(long)m * 512 + n] = accI[mt][nt][r] + vbi;
      }
  }
}

extern "C" void kernel_launch(void* const* d_in, const int* in_sizes, int n_in,
                              void* d_out, int out_size, void* d_ws, size_t ws_size,
                              hipStream_t stream) {
  const float* query_r = (const float*)d_in[0];
  const float* query_i = (const float*)d_in[1];
  const float* key_r   = (const float*)d_in[2];
  const float* key_i   = (const float*)d_in[3];
  const float* value_r = (const float*)d_in[4];
  const float* value_i = (const float*)d_in[5];
  const float* in_w_r  = (const float*)d_in[6];
  const float* in_w_i  = (const float*)d_in[7];
  const float* in_b_r  = (const float*)d_in[8];
  const float* in_b_i  = (const float*)d_in[9];
  const float* out_w_r = (const float*)d_in[10];
  const float* out_w_i = (const float*)d_in[11];
  const float* out_b_r = (const float*)d_in[12];
  const float* out_b_i = (const float*)d_in[13];

  // workspace layout (fp16 elements), total 71,827,456 B
  _Float16* ws = (_Float16*)d_ws;
  _Float16* w16_inr  = ws;                   // 786432   (dead after inproj)
  _Float16* w16_ini  = ws + 786432;          // 786432
  _Float16* w16_outr = ws + 1572864;         // 262144
  _Float16* w16_outi = ws + 1835008;         // 262144
  _Float16* Qp  = ws + 2097152;              // 8388608  (fragment-order)
  _Float16* Kp  = Qp + 8388608;              // 8388608
  _Float16* Vp  = Kp + 8388608;              // 8388608
  _Float16* orh = Vp + 8388608;              // 4194304
  _Float16* oih = orh + 4194304;             // 4194304
  // c overlays the dead in-proj weight region (pass1 runs after inproj)
  float* c_arr = (float*)ws;                 // 65536 fp32

  float* outr = (float*)d_out;               // (T,B,E)
  float* outi = outr + 4194304;              // (T,B,E)
  float* attn = outr + 8388608;              // (B,T,S)

  cvt_weights_kernel<<<1024, 256, 0, stream>>>(in_w_r, in_w_i, out_w_r, out_w_i, ws);

  inproj_kernel<<<dim3(64, 4, 3), 256, 0, stream>>>(
      query_r, query_i, key_r, key_i, value_r, value_i,
      w16_inr, w16_ini, in_b_r, in_b_i,
      Qp, Kp, Vp);

  pass1_kernel<<<256, 512, 0, stream>>>(Qp, Kp, c_arr);

  pass2_kernel<<<256, 512, 0, stream>>>(
      Qp, Kp, Vp, c_arr, orh, oih, attn);

  outproj_kernel<<<dim3(128, 4), 256, 0, stream>>>(
      orh, oih, w16_outr, w16_outi, out_b_r, out_b_i, outr, outi);
}